// Round 8
// baseline (94.556 us; speedup 1.0000x reference)
//
#include <hip/hip_runtime.h>

// SharedMultiCategoricalEncoder on MI355X — round 8: R5 structure + fp16
// packed accumulation.
// x: [B=8192, C=32, L=8] int32 ids in [0, 9311); emb: [9311, 64] fp32 (row 0 zeros).
// out[b,c,:] = sum_l emb[x[b,c,l]] / max(#(x[b,c,l] > 0), 1)
//
// Evidence: traffic x2 = no effect; ILP 8->16 = -5.7us; deeper pipe = flat;
// 2x TLP = worse. Operating point fixed at R5 (2 pairs/thread, 16 outstanding
// gathers, ~4-5 waves/SIMD). This round cuts the unpack/accumulate VALU ~2.5x:
// table staged as fp16 (not bf16), accumulate with v_pk_add_f16 (4 packed adds
// per 128B row-chunk vs 24 shift/and/add ops), unpack to fp32 only in the
// epilogue. fp16 also IMPROVES accuracy vs bf16 (10-bit mantissa): predicted
// absmax ~0.002-0.005 vs threshold 0.0386.

#define NPAIRS (8192 * 32)          // B*C = 262144
#define LL 8
#define NROWS 9311
#define D 64
#define TAB_ELEMS (NROWS * D)       // 595,904
#define HALF_PAIRS (NPAIRS / 2)     // 131072

typedef float    vfloat4 __attribute__((ext_vector_type(4)));
typedef float    vfloat8 __attribute__((ext_vector_type(8)));
typedef int      vint4   __attribute__((ext_vector_type(4)));
typedef _Float16 vhalf8  __attribute__((ext_vector_type(8)));

// ---- prologue: fp32 table -> fp16 (HW RNE via v_cvt_f16_f32) ---------------
__global__ __launch_bounds__(256) void
cvt_table_f16(const vfloat8* __restrict__ src, vhalf8* __restrict__ dst, int n8) {
    const int i = blockIdx.x * blockDim.x + threadIdx.x;
    if (i >= n8) return;
    const vfloat8 f = src[i];
    vhalf8 o;
    #pragma unroll
    for (int k = 0; k < 8; ++k) o[k] = (_Float16)f[k];
    dst[i] = o;   // 16 B store
}

// ---- main: 8 lanes/pair, 2 pairs/thread (R5 winning shape) -----------------
__global__ __launch_bounds__(256) void
SharedMultiCategoricalEncoder_kernel(const int* __restrict__ x,
                                     const vhalf8* __restrict__ tab,   // fp16 table
                                     vfloat4* __restrict__ out4) {
    const int tid   = blockIdx.x * blockDim.x + threadIdx.x;
    const int pairA = tid >> 3;            // [0, HALF_PAIRS)
    const int pairB = pairA + HALF_PAIRS;
    const int sub   = tid & 7;             // channel chunk [sub*8, sub*8+8)

    const vint4* xp = (const vint4*)x;
    const vint4 a01 = xp[2 * pairA];
    const vint4 a23 = xp[2 * pairA + 1];
    const vint4 b01 = xp[2 * pairB];
    const vint4 b23 = xp[2 * pairB + 1];
    const int idsA[LL] = { a01.x, a01.y, a01.z, a01.w, a23.x, a23.y, a23.z, a23.w };
    const int idsB[LL] = { b01.x, b01.y, b01.z, b01.w, b23.x, b23.y, b23.z, b23.w };

    // All 16 gathers in flight before any consumption (16 x dwordx4 dests).
    vhalf8 eA[LL], eB[LL];
#pragma unroll
    for (int l = 0; l < LL; ++l) eA[l] = tab[idsA[l] * 8 + sub];
#pragma unroll
    for (int l = 0; l < LL; ++l) eB[l] = tab[idsB[l] * 8 + sub];

    // Packed fp16 accumulation: 4 v_pk_add_f16 per row-chunk.
    vhalf8 accA = (vhalf8)(_Float16)0;
    vhalf8 accB = (vhalf8)(_Float16)0;
    int cntA = 0, cntB = 0;
#pragma unroll
    for (int l = 0; l < LL; ++l) {
        accA += eA[l];
        accB += eB[l];
        cntA += (idsA[l] > 0);
        cntB += (idsB[l] > 0);
    }

    const float sA = 1.0f / (float)(cntA > 0 ? cntA : 1);
    const float sB = 1.0f / (float)(cntB > 0 ? cntB : 1);

    vfloat4 loA, hiA, loB, hiB;
    #pragma unroll
    for (int k = 0; k < 4; ++k) {
        loA[k] = (float)accA[k]     * sA;
        hiA[k] = (float)accA[4 + k] * sA;
        loB[k] = (float)accB[k]     * sB;
        hiB[k] = (float)accB[4 + k] * sB;
    }

    vfloat4* opA = out4 + pairA * 16 + sub * 2;
    vfloat4* opB = out4 + pairB * 16 + sub * 2;
    opA[0] = loA; opA[1] = hiA;
    opB[0] = loB; opB[1] = hiB;
}

extern "C" void kernel_launch(void* const* d_in, const int* in_sizes, int n_in,
                              void* d_out, int out_size, void* d_ws, size_t ws_size,
                              hipStream_t stream) {
    const int*   x   = (const int*)d_in[0];
    const float* emb = (const float*)d_in[1];
    float*       out = (float*)d_out;

    // fp16 table in workspace: 9311*64*2 B = 1.19 MB.
    const int n8 = TAB_ELEMS / 8;                      // 74,488
    cvt_table_f16<<<(n8 + 255) / 256, 256, 0, stream>>>(
        (const vfloat8*)emb, (vhalf8*)d_ws, n8);

    const int threads = 256;
    const int blocks  = (HALF_PAIRS * 8) / threads;    // 4096 blocks
    SharedMultiCategoricalEncoder_kernel<<<blocks, threads, 0, stream>>>(
        x, (const vhalf8*)d_ws, (vfloat4*)out);
}